// Round 4
// baseline (746.796 us; speedup 1.0000x reference)
//
#include <hip/hip_runtime.h>
#include <hip/hip_bf16.h>

typedef __bf16 bf16x8 __attribute__((ext_vector_type(8)));
typedef float floatx4 __attribute__((ext_vector_type(4)));

#define AS1 __attribute__((address_space(1)))
#define AS3 __attribute__((address_space(3)))

// ---------------------------------------------------------------- cvt A fp32 -> bf16
// Standalone again (R1's fused prep gave cvt blocks a useless 33KB LDS alloc).
__global__ __launch_bounds__(256) void cvt_a_kernel(const float* __restrict__ A,
                                                    __hip_bfloat16* __restrict__ Ab,
                                                    int n8) {
    int i = blockIdx.x * 256 + threadIdx.x;
    if (i >= n8) return;
    size_t base = (size_t)i * 8;
    float4 a0 = *(const float4*)(A + base);
    float4 a1 = *(const float4*)(A + base + 4);
    union { __hip_bfloat16 h[8]; float4 f; } u;
    u.h[0] = __float2bfloat16(a0.x);
    u.h[1] = __float2bfloat16(a0.y);
    u.h[2] = __float2bfloat16(a0.z);
    u.h[3] = __float2bfloat16(a0.w);
    u.h[4] = __float2bfloat16(a1.x);
    u.h[5] = __float2bfloat16(a1.y);
    u.h[6] = __float2bfloat16(a1.z);
    u.h[7] = __float2bfloat16(a1.w);
    *(float4*)(Ab + base) = u.f;
}

// ---------------------------------------------------------------- fused GEMM
// C = A * dequant(Bp,s)^T + bias.  R7: int4 dequant fused into B-staging.
// R5/R6 post-mortem: all schedule-depth refinements neutral at ~46% MfmaUtil;
// the big remaining costs are the prep pipeline (~217us vs ~35us roofline) and
// the Wt intermediate (96MB write + re-fetch, GEMM FETCH=449MB). Fix: B stays
// int4-packed in HBM (4KB/tile vs 16KB bf16); each thread loads one int2 + one
// scale a tile ahead, dequants in-register (exact: as_float(0x4B000000|q) -
// 8388616.0f is Sterbenz-exact q-8, then *sc -> bit-identical to old path),
// and ds_writes straight into the swizzled LDS slots (write side may scatter;
// read side unchanged: slot = chunk ^ ((row>>1)&3); write pattern verified
// conflict-free per 8-lane phase). A stays global_load_lds width=16.
// Schedule: simplest correct form - 2 LDS buffers (64KiB), ONE __syncthreads
// per BK=32 tile, staging for t+1 issued before the MFMA block, waves drift
// freely within the tile region (max compiler-scheduling freedom; every
// tighter structure tested was neutral).
#define GLDS(gp, lp) __builtin_amdgcn_global_load_lds((AS1 void*)(gp), (AS3 void*)(lp), 16, 0, 0)

struct PB { int2 v; float sc; };

// dequant one thread's int2 (16 nibbles = 16 k-values of one column) -> LDS
#define DQW(PBX, nbptr)                                                        \
    do {                                                                       \
        union { __hip_bfloat16 h[8]; float4 f; } u0_, u1_;                     \
        const float sc_ = (PBX).sc;                                            \
        _Pragma("unroll") for (int r_ = 0; r_ < 8; ++r_) {                     \
            u0_.h[r_] = __float2bfloat16(                                      \
                (__uint_as_float(0x4B000000u | (((unsigned)(PBX).v.x >> (4 * r_)) & 0xFu)) \
                 - 8388616.0f) * sc_);                                         \
            u1_.h[r_] = __float2bfloat16(                                      \
                (__uint_as_float(0x4B000000u | (((unsigned)(PBX).v.y >> (4 * r_)) & 0xFu)) \
                 - 8388616.0f) * sc_);                                         \
        }                                                                      \
        *(float4*)((nbptr) + 8192 + dqo0) = u0_.f;                             \
        *(float4*)((nbptr) + 8192 + dqo1) = u1_.f;                             \
    } while (0)

// PBD: packed regs for tile tt+1 (dequanted now); PBL: dest regs for tile tt+2
#define TILE_F(tt, PBD, PBL, DO_STAGE, DO_LOAD, DO_BAR)                        \
    do {                                                                       \
        const int cur_ = (tt) & 1;                                             \
        const __hip_bfloat16* cb_ = lds + cur_ * 16384;                        \
        if (DO_STAGE) {                                                        \
            __hip_bfloat16* nb_ = lds + (cur_ ^ 1) * 16384;                    \
            GLDS(Astg + (size_t)((tt) + 1) * 32, nb_ + ldstA);                 \
            GLDS(Astg + (size_t)((tt) + 1) * 32 + (size_t)128 * K, nb_ + 4096 + ldstA); \
            DQW(PBD, nb_);                                                     \
        }                                                                      \
        if (DO_LOAD) {                                                         \
            (PBL).v = *(const int2*)(Bq + (size_t)((tt) + 2) * 4 * N);         \
            (PBL).sc = sq[(size_t)(((tt) + 2) >> 2) * N];                      \
        }                                                                      \
        bf16x8 af_[8], bf_[4];                                                 \
        _Pragma("unroll") for (int i_ = 0; i_ < 8; ++i_)                       \
            af_[i_] = *(const bf16x8*)&cb_[aoff + i_ * 512];                   \
        _Pragma("unroll") for (int j_ = 0; j_ < 4; ++j_)                       \
            bf_[j_] = *(const bf16x8*)&cb_[8192 + boff + j_ * 512];            \
        __builtin_amdgcn_s_setprio(1);                                         \
        _Pragma("unroll") for (int i_ = 0; i_ < 8; ++i_) {                     \
            _Pragma("unroll") for (int j_ = 0; j_ < 4; ++j_)                   \
                acc[i_][j_] = __builtin_amdgcn_mfma_f32_16x16x32_bf16(         \
                    af_[i_], bf_[j_], acc[i_][j_], 0, 0, 0);                   \
        }                                                                      \
        __builtin_amdgcn_s_setprio(0);                                         \
        if (DO_BAR) __syncthreads();                                           \
    } while (0)

__global__ __launch_bounds__(512, 2) void gemm_fused_kernel(const __hip_bfloat16* __restrict__ A,
                                                            const int* __restrict__ Bp,
                                                            const float* __restrict__ s,
                                                            const float* __restrict__ bias,
                                                            float* __restrict__ C,
                                                            int M, int N, int K) {
    extern __shared__ __hip_bfloat16 lds[];  // 32768 elems = 64 KiB: 2 x (A 8192 | B 8192)

    const int nby = M >> 8;
    const int nbx = N >> 8;
    const int nwg = nbx * nby;
    int id = (int)blockIdx.x;
    if ((nwg & 7) == 0) {  // XCD-contiguous bijective remap
        const int cpx = nwg >> 3;
        id = (id & 7) * cpx + (id >> 3);
    }
    const int bx = id / nby;        // by-fast within bx columns (B-panel L2 reuse)
    const int by = id - bx * nby;
    const int m0 = by << 8;
    const int n0 = bx << 8;

    const int tid = (int)threadIdx.x;
    const int wave = tid >> 6;
    const int lane = tid & 63;
    const int wm = wave >> 2;  // 0..1
    const int wn = wave & 3;   // 0..3
    const int ln = lane & 15;
    const int qd = lane >> 4;              // k-chunk quad
    const int sw = (ln >> 1) & 3;          // read-side slot key ((row>>1)&3)

    // ---- A staging (global_load_lds): wave covers 16 rows x 64B, pre-swizzled src
    const int srow = (wave << 4) + (lane >> 2);               // 0..127 (round 0)
    const int schunk = (lane & 3) ^ ((lane >> 3) & 3);        // slot ^ ((row>>1)&3)
    const __hip_bfloat16* Astg = A + (size_t)(m0 + srow) * K + schunk * 8;
    const int ldstA = (wave << 9);         // wave-uniform LDS dst (elems)

    // ---- B packed staging: thread -> (toff = t-row within tile, nl = column)
    const int toff = tid >> 8;             // 0..1
    const int nl = tid & 255;              // 0..255
    const int* Bq = Bp + (size_t)toff * 2 * N + 2 * (n0 + nl);
    const float* sq = s + n0 + nl;
    const int key = (nl >> 1) & 3;
    const int dqo0 = nl * 32 + (((toff << 1) ^ key) << 3);
    const int dqo1 = nl * 32 + ((((toff << 1) | 1) ^ key) << 3);

    // ---- fragment read offsets (swizzled chunk = logical ^ key)
    const int aoff = (wm * 128 + ln) * 32 + ((qd ^ sw) << 3);
    const int boff = (wn * 64 + ln) * 32 + ((qd ^ sw) << 3);

    floatx4 acc[8][4];
#pragma unroll
    for (int i = 0; i < 8; ++i)
#pragma unroll
        for (int j = 0; j < 4; ++j) acc[i][j] = (floatx4){0.f, 0.f, 0.f, 0.f};

    const int nkt = K >> 5;  // BK=32 tiles (128 here; assumed even, >=4)

    // ---- prologue: fill buf0 with tile 0 (A via GLDS, B via reg-dequant)
    PB pBa, pBb;
    {
        PB p0;
        p0.v = *(const int2*)(Bq);
        p0.sc = sq[0];
        GLDS(Astg, lds + ldstA);
        GLDS(Astg + (size_t)128 * K, lds + 4096 + ldstA);
        asm volatile("s_waitcnt vmcnt(0)" ::: "memory");
        DQW(p0, lds);
        pBa.v = *(const int2*)(Bq + (size_t)4 * N);   // tile 1
        pBa.sc = sq[0];                                // (1*32)>>7 = 0
        __syncthreads();
    }

    int t = 0;
    for (; t + 2 < nkt; t += 2) {
        TILE_F(t,     pBa, pBb, 1, 1, 1);
        TILE_F(t + 1, pBb, pBa, 1, 1, 1);
    }
    TILE_F(t,     pBa, pBb, 1, 0, 1); ++t;   // stages tile nkt-1
    TILE_F(t,     pBb, pBa, 0, 0, 0);        // last tile: compute only

    // ---- epilogue: C/D layout col=lane&15, row=(lane>>4)*4+reg  [m89-verified]
    const int cl = lane & 15;
    const int rq = (lane >> 4) << 2;
#pragma unroll
    for (int j = 0; j < 4; ++j) {
        const int n = n0 + wn * 64 + j * 16 + cl;
        const float bv = bias[n];
#pragma unroll
        for (int i = 0; i < 8; ++i) {
            const int mb = m0 + wm * 128 + i * 16 + rq;
#pragma unroll
            for (int r = 0; r < 4; ++r) {
                float v = acc[i][j][r] + bv;
                __builtin_nontemporal_store(v, &C[(size_t)(mb + r) * N + n]);
            }
        }
    }
}

// ---------------------------------------------------------------- launch
extern "C" void kernel_launch(void* const* d_in, const int* in_sizes, int n_in,
                              void* d_out, int out_size, void* d_ws, size_t ws_size,
                              hipStream_t stream) {
    const float* A = (const float*)d_in[0];
    const int* Bp = (const int*)d_in[1];
    const float* s = (const float*)d_in[2];
    const float* bias = (const float*)d_in[3];
    float* C = (float*)d_out;

    const int N = in_sizes[3];                        // 12288
    const long Bsz = (long)in_sizes[1];               // (K/16)*(2N)
    const int K = (int)(Bsz / (2L * N)) * 16;         // 4096
    const int M = (int)((long)in_sizes[0] / K);       // 4096

    __hip_bfloat16* Ab = (__hip_bfloat16*)d_ws;       // M*K*2 B (only ws use now)

    // 64 KiB dynamic LDS opt-in (host-side attr set, capture-safe)
    static int attr_done = 0;
    if (!attr_done) {
        (void)hipFuncSetAttribute((const void*)gemm_fused_kernel,
                                  hipFuncAttributeMaxDynamicSharedMemorySize, 65536);
        attr_done = 1;
    }

    const int n8 = (M * K) / 8;
    cvt_a_kernel<<<(n8 + 255) / 256, 256, 0, stream>>>(A, Ab, n8);
    const int nwg = (M >> 8) * (N >> 8);              // 768, %8==0
    gemm_fused_kernel<<<nwg, 512, 65536, stream>>>(Ab, Bp, s, bias, C, M, N, K);
}

// Round 5
// 706.009 us; speedup vs baseline: 1.0578x; 1.0578x over previous
//
#include <hip/hip_runtime.h>
#include <hip/hip_bf16.h>

typedef __bf16 bf16x8 __attribute__((ext_vector_type(8)));
typedef float floatx4 __attribute__((ext_vector_type(4)));

#define AS1 __attribute__((address_space(1)))
#define AS3 __attribute__((address_space(3)))

// ---------------------------------------------------------------- cvt A fp32 -> bf16
__global__ __launch_bounds__(256) void cvt_a_kernel(const float* __restrict__ A,
                                                    __hip_bfloat16* __restrict__ Ab,
                                                    int n8) {
    int i = blockIdx.x * 256 + threadIdx.x;
    if (i >= n8) return;
    size_t base = (size_t)i * 8;
    float4 a0 = *(const float4*)(A + base);
    float4 a1 = *(const float4*)(A + base + 4);
    union { __hip_bfloat16 h[8]; float4 f; } u;
    u.h[0] = __float2bfloat16(a0.x);
    u.h[1] = __float2bfloat16(a0.y);
    u.h[2] = __float2bfloat16(a0.z);
    u.h[3] = __float2bfloat16(a0.w);
    u.h[4] = __float2bfloat16(a1.x);
    u.h[5] = __float2bfloat16(a1.y);
    u.h[6] = __float2bfloat16(a1.z);
    u.h[7] = __float2bfloat16(a1.w);
    *(float4*)(Ab + base) = u.f;
}

// ---------------------------------------------------------------- fused GEMM
// C = A * dequant(Bp,s)^T + bias.
// R8 = R7's fused dequant (kept: FETCH -43MB, one kernel less, bit-identical
// numerics) + R4's counted-vmcnt raw-barrier schedule (restored: R7's
// __syncthreads drained vmcnt(0) ~320cyc after staging issue -> ~580cyc HBM
// latency exposed per tile -> MfmaUtil 46->31).
// Structure: 4 LDS buffers x 32KiB (128KiB). BK=32. Per tile t:
//   issue t+2 staging (2 A-GLDS -> buf[t+2], B int2+scale -> regs; 4 vm ops)
//   ds_read frags of tile t from buf[t]; 32 MFMA @ setprio(1)
//   s_waitcnt vmcnt(4)   <- completes OLDEST 4 = tile t+1's ops (FIFO, m135);
//                           t+2's 4 stay in flight. Never 0 in main loop.
//   DQW(B regs of t+1) -> ds_write buf[t+1]
//   s_waitcnt lgkmcnt(0); sched_barrier; s_barrier; sched_barrier
// Readers after barrier see buf[t+1] complete: A via counted vmcnt, B via
// lgkm drain. GLDS(t+2) overwrites buf[t-2], consumed 2 barriers ago (safe).
// "memory"-clobber asm pins all issue ops before the counted waits.
#define GLDS(gp, lp) __builtin_amdgcn_global_load_lds((AS1 void*)(gp), (AS3 void*)(lp), 16, 0, 0)

struct PB { int2 v; float sc; };

// dequant one thread's int2 (16 nibbles = 16 k of one column) -> LDS B region
// exact: as_float(0x4B000000|q) - 8388616.0f == q - 8 (Sterbenz), then *sc
#define DQW(PBX, bufptr)                                                       \
    do {                                                                       \
        union { __hip_bfloat16 h[8]; float4 f; } u0_, u1_;                     \
        const float sc_ = (PBX).sc;                                            \
        _Pragma("unroll") for (int r_ = 0; r_ < 8; ++r_) {                     \
            u0_.h[r_] = __float2bfloat16(                                      \
                (__uint_as_float(0x4B000000u | (((unsigned)(PBX).v.x >> (4 * r_)) & 0xFu)) \
                 - 8388616.0f) * sc_);                                         \
            u1_.h[r_] = __float2bfloat16(                                      \
                (__uint_as_float(0x4B000000u | (((unsigned)(PBX).v.y >> (4 * r_)) & 0xFu)) \
                 - 8388616.0f) * sc_);                                         \
        }                                                                      \
        *(float4*)((bufptr) + 8192 + dqo0) = u0_.f;                            \
        *(float4*)((bufptr) + 8192 + dqo1) = u1_.f;                            \
    } while (0)

#define VM4 asm volatile("s_waitcnt vmcnt(4)" ::: "memory")
#define VM0 asm volatile("s_waitcnt vmcnt(0)" ::: "memory")
#define VMN ((void)0)
#define END_BAR()                                                              \
    do {                                                                       \
        asm volatile("s_waitcnt lgkmcnt(0)" ::: "memory");                     \
        __builtin_amdgcn_sched_barrier(0);                                     \
        __builtin_amdgcn_s_barrier();                                          \
        __builtin_amdgcn_sched_barrier(0);                                     \
    } while (0)

// PBL: regs to fill with B(tt+2); PBD: regs holding B(tt+1), dequanted now
#define TILE_R8(tt, PBL, PBD, DO_ISSUE, VWAIT, DO_DQ, DO_BAR)                  \
    do {                                                                       \
        const __hip_bfloat16* cb_ = lds + ((tt) & 3) * 16384;                  \
        if (DO_ISSUE) {                                                        \
            __hip_bfloat16* sb_ = lds + (((tt) + 2) & 3) * 16384;              \
            GLDS(Astg + (size_t)((tt) + 2) * 32, sb_ + ldstA);                 \
            GLDS(Astg + (size_t)((tt) + 2) * 32 + (size_t)128 * K, sb_ + 4096 + ldstA); \
            (PBL).v = *(const int2*)(Bq + (size_t)((tt) + 2) * 4 * N);         \
            (PBL).sc = sq[(size_t)(((tt) + 2) >> 2) * N];                      \
        }                                                                      \
        bf16x8 af_[8], bf_[4];                                                 \
        _Pragma("unroll") for (int i_ = 0; i_ < 8; ++i_)                       \
            af_[i_] = *(const bf16x8*)&cb_[aoff + i_ * 512];                   \
        _Pragma("unroll") for (int j_ = 0; j_ < 4; ++j_)                       \
            bf_[j_] = *(const bf16x8*)&cb_[8192 + boff + j_ * 512];            \
        __builtin_amdgcn_s_setprio(1);                                         \
        _Pragma("unroll") for (int i_ = 0; i_ < 8; ++i_) {                     \
            _Pragma("unroll") for (int j_ = 0; j_ < 4; ++j_)                   \
                acc[i_][j_] = __builtin_amdgcn_mfma_f32_16x16x32_bf16(         \
                    af_[i_], bf_[j_], acc[i_][j_], 0, 0, 0);                   \
        }                                                                      \
        __builtin_amdgcn_s_setprio(0);                                         \
        VWAIT;                                                                 \
        if (DO_DQ) {                                                           \
            __hip_bfloat16* db_ = lds + (((tt) + 1) & 3) * 16384;              \
            DQW(PBD, db_);                                                     \
        }                                                                      \
        if (DO_BAR) END_BAR();                                                 \
    } while (0)

__global__ __launch_bounds__(512, 2) void gemm_fused_kernel(const __hip_bfloat16* __restrict__ A,
                                                            const int* __restrict__ Bp,
                                                            const float* __restrict__ s,
                                                            const float* __restrict__ bias,
                                                            float* __restrict__ C,
                                                            int M, int N, int K) {
    extern __shared__ __hip_bfloat16 lds[];  // 65536 elems = 128 KiB: 4 x (A 8192 | B 8192)

    const int nby = M >> 8;
    const int nbx = N >> 8;
    const int nwg = nbx * nby;
    int id = (int)blockIdx.x;
    if ((nwg & 7) == 0) {  // XCD-contiguous bijective remap
        const int cpx = nwg >> 3;
        id = (id & 7) * cpx + (id >> 3);
    }
    const int bx = id / nby;        // by-fast within bx columns (B-panel L2 reuse)
    const int by = id - bx * nby;
    const int m0 = by << 8;
    const int n0 = bx << 8;

    const int tid = (int)threadIdx.x;
    const int wave = tid >> 6;
    const int lane = tid & 63;
    const int wm = wave >> 2;  // 0..1
    const int wn = wave & 3;   // 0..3
    const int ln = lane & 15;
    const int qd = lane >> 4;              // k-chunk quad
    const int sw = (ln >> 1) & 3;          // read-side slot key ((row>>1)&3)

    // ---- A staging (global_load_lds): wave covers 16 rows x 64B, pre-swizzled src
    const int srow = (wave << 4) + (lane >> 2);               // 0..127 (round 0)
    const int schunk = (lane & 3) ^ ((lane >> 3) & 3);        // slot ^ ((row>>1)&3)
    const __hip_bfloat16* Astg = A + (size_t)(m0 + srow) * K + schunk * 8;
    const int ldstA = (wave << 9);         // wave-uniform LDS dst (elems)

    // ---- B packed staging: thread -> (toff = t-row within tile, nl = column)
    const int toff = tid >> 8;             // 0..1
    const int nl = tid & 255;              // 0..255
    const int* Bq = Bp + (size_t)toff * 2 * N + 2 * (n0 + nl);
    const float* sq = s + n0 + nl;
    const int key = (nl >> 1) & 3;
    const int dqo0 = nl * 32 + (((toff << 1) ^ key) << 3);
    const int dqo1 = nl * 32 + ((((toff << 1) | 1) ^ key) << 3);

    // ---- fragment read offsets (swizzled chunk = logical ^ key)
    const int aoff = (wm * 128 + ln) * 32 + ((qd ^ sw) << 3);
    const int boff = (wn * 64 + ln) * 32 + ((qd ^ sw) << 3);

    floatx4 acc[8][4];
#pragma unroll
    for (int i = 0; i < 8; ++i)
#pragma unroll
        for (int j = 0; j < 4; ++j) acc[i][j] = (floatx4){0.f, 0.f, 0.f, 0.f};

    const int nkt = K >> 5;  // BK=32 tiles (128 here; nkt even, >=4)

    // ---- prologue: issue tiles 0,1; force tile 0 (oldest 4) complete; DQ B0
    PB pb0, pb1;
    GLDS(Astg, lds + ldstA);
    GLDS(Astg + (size_t)128 * K, lds + 4096 + ldstA);
    pb0.v = *(const int2*)(Bq);
    pb0.sc = sq[0];
    GLDS(Astg + 32, lds + 16384 + ldstA);
    GLDS(Astg + 32 + (size_t)128 * K, lds + 16384 + 4096 + ldstA);
    pb1.v = *(const int2*)(Bq + (size_t)4 * N);
    pb1.sc = sq[0];                        // (1*32)>>7 = group 0
    VM4;                                   // tile0's A-GLDS + pb0 landed
    DQW(pb0, lds);                         // B0 -> buf0
    END_BAR();

    int t = 0;
    for (; t + 4 <= nkt; t += 2) {
        TILE_R8(t,     pb0, pb1, 1, VM4, 1, 1);  // issue t+2->pb0; DQ B(t+1)=pb1
        TILE_R8(t + 1, pb1, pb0, 1, VM4, 1, 1);  // issue t+3->pb1; DQ B(t+2)=pb0
    }
    // t == nkt-2: no more issues; drain last tile's loads; DQ B(nkt-1)
    TILE_R8(t, pb0, pb1, 0, VM0, 1, 1); ++t;
    TILE_R8(t, pb0, pb0, 0, VMN, 0, 0);          // last tile: compute only

    // ---- epilogue: C/D layout col=lane&15, row=(lane>>4)*4+reg  [m89-verified]
    const int cl = lane & 15;
    const int rq = (lane >> 4) << 2;
#pragma unroll
    for (int j = 0; j < 4; ++j) {
        const int n = n0 + wn * 64 + j * 16 + cl;
        const float bv = bias[n];
#pragma unroll
        for (int i = 0; i < 8; ++i) {
            const int mb = m0 + wm * 128 + i * 16 + rq;
#pragma unroll
            for (int r = 0; r < 4; ++r) {
                float v = acc[i][j][r] + bv;
                __builtin_nontemporal_store(v, &C[(size_t)(mb + r) * N + n]);
            }
        }
    }
}

// ---------------------------------------------------------------- launch
extern "C" void kernel_launch(void* const* d_in, const int* in_sizes, int n_in,
                              void* d_out, int out_size, void* d_ws, size_t ws_size,
                              hipStream_t stream) {
    const float* A = (const float*)d_in[0];
    const int* Bp = (const int*)d_in[1];
    const float* s = (const float*)d_in[2];
    const float* bias = (const float*)d_in[3];
    float* C = (float*)d_out;

    const int N = in_sizes[3];                        // 12288
    const long Bsz = (long)in_sizes[1];               // (K/16)*(2N)
    const int K = (int)(Bsz / (2L * N)) * 16;         // 4096
    const int M = (int)((long)in_sizes[0] / K);       // 4096

    __hip_bfloat16* Ab = (__hip_bfloat16*)d_ws;       // M*K*2 B

    // 128 KiB dynamic LDS opt-in (host-side attr set, capture-safe)
    static int attr_done = 0;
    if (!attr_done) {
        (void)hipFuncSetAttribute((const void*)gemm_fused_kernel,
                                  hipFuncAttributeMaxDynamicSharedMemorySize, 131072);
        attr_done = 1;
    }

    const int n8 = (M * K) / 8;
    cvt_a_kernel<<<(n8 + 255) / 256, 256, 0, stream>>>(A, Ab, n8);
    const int nwg = (M >> 8) * (N >> 8);              // 768, %8==0
    gemm_fused_kernel<<<nwg, 512, 131072, stream>>>(Ab, Bp, s, bias, C, M, N, K);
}